// Round 4
// baseline (58.139 us; speedup 1.0000x reference)
//
#include <hip/hip_runtime.h>
#include <hip/hip_cooperative_groups.h>

namespace cg = cooperative_groups;

// B=4, H=512, W=512 (from setup_inputs)
#define B_   4
#define H_   512
#define W_   512
#define HW_  (H_ * W_)

#define NBLK 512    // 128 spatial blocks x 4 batches; 2 blocks/CU -> co-resident
#define NTHR 256

// Semantics (verified exact in R2/R3, absmax 0.0):
//   c0[p]  = #{b : !(pred[b,1,p] > pred[b,0,p])}                (argmax ties -> 0)
//   S[a,p] = pred[a,0,p]*c0 - pred[a,1,p]*(4-c0)
//   per neighbor (zero-padded gt & heights; pad counts as valid dry):
//     ign = (g != 255); gr = (g==0 ? -1 : 1); delta = hc - hn
//     keep = !(gr*delta > 0)
//     loss += ign && keep ? (4 - gr*S) : 0;  n_valid += ign
//   out = loss / max(n_valid, 1)
__global__ __launch_bounds__(NTHR) void elev_coop(
    const float* __restrict__ pred,
    const float* __restrict__ hts,
    const float* __restrict__ gt,
    unsigned long long* __restrict__ partial,   // NBLK pairs
    float* __restrict__ out)
{
    const int a     = blockIdx.x >> 7;              // batch handled by this block
    const int sb    = blockIdx.x & 127;             // spatial block
    const int chunk = sb * NTHR + threadIdx.x;      // [0, 32768): 8-px chunks
    const int px0   = chunk << 3;
    const int i     = px0 >> 9;
    const int j0    = px0 & (W_ - 1);

    // ---- cross-batch argmax counts for the 8 pixels ----
    int c0k[8] = {0, 0, 0, 0, 0, 0, 0, 0};
    #pragma unroll
    for (int b = 0; b < B_; ++b) {
        const float* p0p = pred + (size_t)(b * 2) * HW_ + px0;
        const float4 x0 = *(const float4*)(p0p);
        const float4 x1 = *(const float4*)(p0p + 4);
        const float4 y0 = *(const float4*)(p0p + HW_);
        const float4 y1 = *(const float4*)(p0p + HW_ + 4);
        c0k[0] += (y0.x > x0.x) ? 0 : 1;
        c0k[1] += (y0.y > x0.y) ? 0 : 1;
        c0k[2] += (y0.z > x0.z) ? 0 : 1;
        c0k[3] += (y0.w > x0.w) ? 0 : 1;
        c0k[4] += (y1.x > x1.x) ? 0 : 1;
        c0k[5] += (y1.y > x1.y) ? 0 : 1;
        c0k[6] += (y1.z > x1.z) ? 0 : 1;
        c0k[7] += (y1.w > x1.w) ? 0 : 1;
    }

    // ---- own batch S[k] (pred re-load hits L1) ----
    float S[8];
    {
        const float* p0p = pred + (size_t)(a * 2) * HW_ + px0;
        const float4 x0 = *(const float4*)(p0p);
        const float4 x1 = *(const float4*)(p0p + 4);
        const float4 y0 = *(const float4*)(p0p + HW_);
        const float4 y1 = *(const float4*)(p0p + HW_ + 4);
        const float xs[8] = {x0.x, x0.y, x0.z, x0.w, x1.x, x1.y, x1.z, x1.w};
        const float ys[8] = {y0.x, y0.y, y0.z, y0.w, y1.x, y1.y, y1.z, y1.w};
        #pragma unroll
        for (int k = 0; k < 8; ++k) {
            const float c0f = (float)c0k[k];
            S[k] = xs[k] * c0f - ys[k] * ((float)B_ - c0f);
        }
    }

    const float* hbase = hts + (size_t)a * HW_;
    const float* gbase = gt  + (size_t)a * HW_;

    // center heights
    float hc[8];
    {
        const float* hrow = hbase + (size_t)i * W_ + j0;
        const float4 h0 = *(const float4*)(hrow);
        const float4 h1 = *(const float4*)(hrow + 4);
        hc[0] = h0.x; hc[1] = h0.y; hc[2] = h0.z; hc[3] = h0.w;
        hc[4] = h1.x; hc[5] = h1.y; hc[6] = h1.z; hc[7] = h1.w;
    }

    const int  idxL = (j0 > 0) ? (j0 - 1) : 0;            // clamped, always in-bounds
    const int  idxR = (j0 < W_ - 8) ? (j0 + 8) : (W_ - 1);
    const bool lv   = (j0 > 0);
    const bool rv   = (j0 < W_ - 8);

    float lacc = 0.0f;
    int   vcnt = 0;

    #pragma unroll
    for (int dr = 0; dr < 3; ++dr) {
        const int  r    = i + dr - 1;
        const int  rc   = (r < 0) ? 0 : ((r > H_ - 1) ? (H_ - 1) : r);
        const bool rowv = (r == rc);
        const float* hrow = hbase + (size_t)rc * W_;
        const float* grow = gbase + (size_t)rc * W_;

        const float4 h0 = *(const float4*)(hrow + j0);
        const float4 h1 = *(const float4*)(hrow + j0 + 4);
        const float  hl  = hrow[idxL];
        const float  hr2 = hrow[idxR];
        const float4 g0 = *(const float4*)(grow + j0);
        const float4 g1 = *(const float4*)(grow + j0 + 4);
        const float  gl  = grow[idxL];
        const float  gr2 = grow[idxR];

        // 10-wide zero-padded windows (pad entries PARTICIPATE as g=0,h=0)
        float wh[10], wg[10];
        {
            const float hm[8] = {h0.x, h0.y, h0.z, h0.w, h1.x, h1.y, h1.z, h1.w};
            const float gm[8] = {g0.x, g0.y, g0.z, g0.w, g1.x, g1.y, g1.z, g1.w};
            #pragma unroll
            for (int c = 0; c < 8; ++c) {
                wh[c + 1] = rowv ? hm[c] : 0.0f;
                wg[c + 1] = rowv ? gm[c] : 0.0f;
            }
        }
        wh[0] = (rowv && lv) ? hl  : 0.0f;
        wg[0] = (rowv && lv) ? gl  : 0.0f;
        wh[9] = (rowv && rv) ? hr2 : 0.0f;
        wg[9] = (rowv && rv) ? gr2 : 0.0f;

        #pragma unroll
        for (int k = 0; k < 8; ++k) {
            #pragma unroll
            for (int d = 0; d < 3; ++d) {
                const float g     = wg[k + d];
                const float hn    = wh[k + d];
                const bool  ign   = (g != 255.0f);
                const float grv   = (g == 0.0f) ? -1.0f : 1.0f;
                const float delta = hc[k] - hn;
                const bool  keep  = !(grv * delta > 0.0f);
                const float sc    = 4.0f - grv * S[k];
                lacc += (ign && keep) ? sc : 0.0f;
                vcnt += ign ? 1 : 0;
            }
        }
    }

    // ---- block reduce ----
    double l = (double)lacc;
    double v = (double)vcnt;
    for (int off = 32; off > 0; off >>= 1) {
        l += __shfl_down(l, off, 64);
        v += __shfl_down(v, off, 64);
    }
    __shared__ double s_l[NTHR / 64];
    __shared__ double s_v[NTHR / 64];
    const int wave = threadIdx.x >> 6;
    const int lane = threadIdx.x & 63;
    if (lane == 0) { s_l[wave] = l; s_v[wave] = v; }
    __syncthreads();
    if (threadIdx.x == 0) {
        const double bl = s_l[0] + s_l[1] + s_l[2] + s_l[3];
        const double bv = s_v[0] + s_v[1] + s_v[2] + s_v[3];
        // device-scope coherent writes (cross-XCD visible; proven pattern from R3)
        atomicExch(&partial[2 * (size_t)blockIdx.x],     (unsigned long long)__double_as_longlong(bl));
        atomicExch(&partial[2 * (size_t)blockIdx.x + 1], (unsigned long long)__double_as_longlong(bv));
    }

    // ---- single-dispatch grid-wide barrier ----
    cg::this_grid().sync();

    // ---- block 0 folds all partials in fixed index order (deterministic) ----
    if (blockIdx.x == 0) {
        double tl = 0.0, tv = 0.0;
        #pragma unroll
        for (int q = 0; q < NBLK / NTHR; ++q) {
            const size_t idx = (size_t)(q * NTHR + threadIdx.x);
            // atomic read-of-0 => coherent cross-XCD read (proven pattern from R3)
            tl += __longlong_as_double((long long)atomicAdd(&partial[2 * idx],     0ull));
            tv += __longlong_as_double((long long)atomicAdd(&partial[2 * idx + 1], 0ull));
        }
        for (int off = 32; off > 0; off >>= 1) {
            tl += __shfl_down(tl, off, 64);
            tv += __shfl_down(tv, off, 64);
        }
        if (lane == 0) { s_l[wave] = tl; s_v[wave] = tv; }
        __syncthreads();
        if (threadIdx.x == 0) {
            const double fl = s_l[0] + s_l[1] + s_l[2] + s_l[3];
            const double fv = s_v[0] + s_v[1] + s_v[2] + s_v[3];
            out[0] = (float)(fl / (fv > 1.0 ? fv : 1.0));
        }
    }
}

extern "C" void kernel_launch(void* const* d_in, const int* in_sizes, int n_in,
                              void* d_out, int out_size, void* d_ws, size_t ws_size,
                              hipStream_t stream) {
    const float* pred = (const float*)d_in[0];   // (4,2,512,512) f32
    const float* hts  = (const float*)d_in[1];   // (4,1,512,512) f32
    const float* gt   = (const float*)d_in[2];   // (4,1,512,512) f32
    float* out        = (float*)d_out;
    unsigned long long* partial = (unsigned long long*)d_ws;   // 512*2*8B = 8 KiB

    void* args[] = { (void*)&pred, (void*)&hts, (void*)&gt, (void*)&partial, (void*)&out };
    hipLaunchCooperativeKernel((const void*)elev_coop, dim3(NBLK), dim3(NTHR),
                               args, 0, stream);
}

// Round 5
// 52.025 us; speedup vs baseline: 1.1175x; 1.1175x over previous
//
#include <hip/hip_runtime.h>

// B=4, H=512, W=512 (from setup_inputs)
#define B_   4
#define H_   512
#define W_   512
#define HW_  (H_ * W_)

#define NBLK 2048   // 512 spatial blocks x 4 batches; 8 blocks/CU -> 32 waves/CU
#define NTHR 256

// Semantics (verified exact in R2/R3/R4, absmax 0.0):
//   c0[p]  = #{b : !(pred[b,1,p] > pred[b,0,p])}                (argmax ties -> 0)
//   S[a,p] = pred[a,0,p]*c0 - pred[a,1,p]*(4-c0)
//   per neighbor (zero-padded gt & heights; pad counts as valid dry):
//     ign = (g != 255); gr = (g==0 ? -1 : 1); delta = hc - hn
//     keep = !(gr*delta > 0)
//     loss += ign && keep ? (4 - gr*S) : 0;  n_valid += ign
//   out = loss / max(n_valid, 1)
__global__ __launch_bounds__(NTHR) void elev_fused2(
    const float* __restrict__ pred,
    const float* __restrict__ hts,
    const float* __restrict__ gt,
    unsigned long long* __restrict__ partial,   // NBLK pairs
    unsigned int* __restrict__ counter,
    float* __restrict__ out)
{
    const int a     = blockIdx.x >> 9;              // batch 0..3
    const int sb    = blockIdx.x & 511;             // spatial block
    const int chunk = sb * NTHR + threadIdx.x;      // [0, 131072): 2-px chunks
    const int px0   = chunk << 1;
    const int i     = px0 >> 9;
    const int j0    = px0 & (W_ - 1);

    // ---- cross-batch argmax counts for the 2 pixels (keep own batch's values) ----
    int c00 = 0, c01 = 0;
    float xax = 0.f, xay = 0.f, yax = 0.f, yay = 0.f;
    #pragma unroll
    for (int b = 0; b < B_; ++b) {
        const float* pb = pred + (size_t)(b * 2) * HW_ + px0;
        const float2 x = *(const float2*)(pb);
        const float2 y = *(const float2*)(pb + HW_);
        c00 += (y.x > x.x) ? 0 : 1;
        c01 += (y.y > x.y) ? 0 : 1;
        if (b == a) { xax = x.x; xay = x.y; yax = y.x; yay = y.y; }
    }
    const float S0 = xax * (float)c00 - yax * (float)(B_ - c00);
    const float S1 = xay * (float)c01 - yay * (float)(B_ - c01);

    const float* hbase = hts + (size_t)a * HW_;
    const float* gbase = gt  + (size_t)a * HW_;

    const float2 hcv = *(const float2*)(hbase + px0);
    const float  hc[2] = { hcv.x, hcv.y };
    const float  S[2]  = { S0, S1 };

    const int  jL = (j0 > 0) ? (j0 - 1) : 0;             // clamped, in-bounds
    const int  jR = (j0 < W_ - 2) ? (j0 + 2) : (W_ - 1);
    const bool lv = (j0 > 0);
    const bool rv = (j0 < W_ - 2);

    float lacc = 0.0f;
    int   vcnt = 0;

    #pragma unroll
    for (int dr = 0; dr < 3; ++dr) {
        const int  r    = i + dr - 1;
        const int  rc   = (r < 0) ? 0 : ((r > H_ - 1) ? (H_ - 1) : r);
        const bool rowv = (r == rc);
        const float* hrow = hbase + (size_t)rc * W_;
        const float* grow = gbase + (size_t)rc * W_;

        const float2 hm = *(const float2*)(hrow + j0);
        const float  hl = hrow[jL];
        const float  hr = hrow[jR];
        const float2 gm = *(const float2*)(grow + j0);
        const float  gl = grow[jL];
        const float  gr = grow[jR];

        // 4-wide zero-padded windows (pad entries PARTICIPATE as g=0,h=0)
        const float wh[4] = { (rowv && lv) ? hl : 0.0f,
                              rowv ? hm.x : 0.0f,
                              rowv ? hm.y : 0.0f,
                              (rowv && rv) ? hr : 0.0f };
        const float wg[4] = { (rowv && lv) ? gl : 0.0f,
                              rowv ? gm.x : 0.0f,
                              rowv ? gm.y : 0.0f,
                              (rowv && rv) ? gr : 0.0f };

        #pragma unroll
        for (int k = 0; k < 2; ++k) {
            #pragma unroll
            for (int d = 0; d < 3; ++d) {
                const float g     = wg[k + d];
                const float hn    = wh[k + d];
                const bool  ign   = (g != 255.0f);
                const float grv   = (g == 0.0f) ? -1.0f : 1.0f;
                const float delta = hc[k] - hn;
                const bool  keep  = !(grv * delta > 0.0f);
                const float sc    = 4.0f - grv * S[k];
                lacc += (ign && keep) ? sc : 0.0f;
                vcnt += ign ? 1 : 0;
            }
        }
    }

    // ---- block reduce ----
    double l = (double)lacc;
    double v = (double)vcnt;
    for (int off = 32; off > 0; off >>= 1) {
        l += __shfl_down(l, off, 64);
        v += __shfl_down(v, off, 64);
    }
    __shared__ double   s_l[NTHR / 64];
    __shared__ double   s_v[NTHR / 64];
    __shared__ unsigned s_old;
    const int wave = threadIdx.x >> 6;
    const int lane = threadIdx.x & 63;
    if (lane == 0) { s_l[wave] = l; s_v[wave] = v; }
    __syncthreads();
    if (threadIdx.x == 0) {
        const double bl = s_l[0] + s_l[1] + s_l[2] + s_l[3];
        const double bv = s_v[0] + s_v[1] + s_v[2] + s_v[3];
        atomicExch(&partial[2 * (size_t)blockIdx.x],     (unsigned long long)__double_as_longlong(bl));
        atomicExch(&partial[2 * (size_t)blockIdx.x + 1], (unsigned long long)__double_as_longlong(bv));
        __threadfence();                       // release: partials visible device-wide
        s_old = atomicAdd(counter, 1u);
    }
    __syncthreads();

    // ---- last block folds all partials in fixed index order (deterministic) ----
    if (s_old == NBLK - 1) {
        double tl = 0.0, tv = 0.0;
        #pragma unroll
        for (int q = 0; q < NBLK / NTHR; ++q) {
            const size_t idx = (size_t)(q * NTHR + threadIdx.x);
            // atomic read-of-0 => coherent cross-XCD read (proven in R3/R4)
            tl += __longlong_as_double((long long)atomicAdd(&partial[2 * idx],     0ull));
            tv += __longlong_as_double((long long)atomicAdd(&partial[2 * idx + 1], 0ull));
        }
        for (int off = 32; off > 0; off >>= 1) {
            tl += __shfl_down(tl, off, 64);
            tv += __shfl_down(tv, off, 64);
        }
        __syncthreads();   // s_l/s_v reuse
        if (lane == 0) { s_l[wave] = tl; s_v[wave] = tv; }
        __syncthreads();
        if (threadIdx.x == 0) {
            const double fl = s_l[0] + s_l[1] + s_l[2] + s_l[3];
            const double fv = s_v[0] + s_v[1] + s_v[2] + s_v[3];
            out[0] = (float)(fl / (fv > 1.0 ? fv : 1.0));
        }
    }
}

extern "C" void kernel_launch(void* const* d_in, const int* in_sizes, int n_in,
                              void* d_out, int out_size, void* d_ws, size_t ws_size,
                              hipStream_t stream) {
    const float* pred = (const float*)d_in[0];   // (4,2,512,512) f32
    const float* hts  = (const float*)d_in[1];   // (4,1,512,512) f32
    const float* gt   = (const float*)d_in[2];   // (4,1,512,512) f32
    float* out        = (float*)d_out;

    unsigned long long* partial = (unsigned long long*)d_ws;   // 2048*2*8B = 32 KiB
    unsigned int* counter = (unsigned int*)((char*)d_ws + 32768);

    hipMemsetAsync(counter, 0, sizeof(unsigned int), stream);  // graph-capture-safe
    elev_fused2<<<NBLK, NTHR, 0, stream>>>(pred, hts, gt, partial, counter, out);
}

// Round 6
// 16.844 us; speedup vs baseline: 3.4517x; 3.0887x over previous
//
#include <hip/hip_runtime.h>

// B=4, H=512, W=512 (from setup_inputs)
#define B_   4
#define H_   512
#define W_   512
#define HW_  (H_ * W_)

#define NBLK 2048   // 512 spatial blocks x 4 batches; 8 blocks/CU -> 32 waves/CU
#define NTHR 256

// Semantics (verified exact R2-R5, absmax 0.0):
//   c0[p]  = #{b : !(pred[b,1,p] > pred[b,0,p])}                (argmax ties -> 0)
//   S[a,p] = pred[a,0,p]*c0 - pred[a,1,p]*(4-c0)
//   per neighbor (zero-padded gt & heights; pad counts as valid dry):
//     ign = (g != 255); gr = (g==0 ? -1 : 1); delta = hc - hn
//     keep = !(gr*delta > 0)
//     loss += ign && keep ? (4 - gr*S) : 0;  n_valid += ign
//   out = loss / max(n_valid, 1)
__global__ __launch_bounds__(NTHR) void elev_partial3(
    const float* __restrict__ pred,
    const float* __restrict__ hts,
    const float* __restrict__ gt,
    double2* __restrict__ partial)              // NBLK entries, plain stores
{
    const int a     = blockIdx.x >> 9;              // batch 0..3
    const int sb    = blockIdx.x & 511;             // spatial block
    const int chunk = sb * NTHR + threadIdx.x;      // [0, 131072): 2-px chunks
    const int px0   = chunk << 1;
    const int i     = px0 >> 9;
    const int j0    = px0 & (W_ - 1);

    // ---- cross-batch argmax counts for the 2 pixels (keep own batch's values) ----
    int c00 = 0, c01 = 0;
    float xax = 0.f, xay = 0.f, yax = 0.f, yay = 0.f;
    #pragma unroll
    for (int b = 0; b < B_; ++b) {
        const float* pb = pred + (size_t)(b * 2) * HW_ + px0;
        const float2 x = *(const float2*)(pb);
        const float2 y = *(const float2*)(pb + HW_);
        c00 += (y.x > x.x) ? 0 : 1;
        c01 += (y.y > x.y) ? 0 : 1;
        if (b == a) { xax = x.x; xay = x.y; yax = y.x; yay = y.y; }
    }
    const float S0 = xax * (float)c00 - yax * (float)(B_ - c00);
    const float S1 = xay * (float)c01 - yay * (float)(B_ - c01);

    const float* hbase = hts + (size_t)a * HW_;
    const float* gbase = gt  + (size_t)a * HW_;

    const float2 hcv = *(const float2*)(hbase + px0);
    const float  hc[2] = { hcv.x, hcv.y };
    const float  S[2]  = { S0, S1 };

    const int  jL = (j0 > 0) ? (j0 - 1) : 0;             // clamped, in-bounds
    const int  jR = (j0 < W_ - 2) ? (j0 + 2) : (W_ - 1);
    const bool lv = (j0 > 0);
    const bool rv = (j0 < W_ - 2);

    float lacc = 0.0f;
    int   vcnt = 0;

    #pragma unroll
    for (int dr = 0; dr < 3; ++dr) {
        const int  r    = i + dr - 1;
        const int  rc   = (r < 0) ? 0 : ((r > H_ - 1) ? (H_ - 1) : r);
        const bool rowv = (r == rc);
        const float* hrow = hbase + (size_t)rc * W_;
        const float* grow = gbase + (size_t)rc * W_;

        const float2 hm = *(const float2*)(hrow + j0);
        const float  hl = hrow[jL];
        const float  hr = hrow[jR];
        const float2 gm = *(const float2*)(grow + j0);
        const float  gl = grow[jL];
        const float  gr = grow[jR];

        // 4-wide zero-padded windows (pad entries PARTICIPATE as g=0,h=0)
        const float wh[4] = { (rowv && lv) ? hl : 0.0f,
                              rowv ? hm.x : 0.0f,
                              rowv ? hm.y : 0.0f,
                              (rowv && rv) ? hr : 0.0f };
        const float wg[4] = { (rowv && lv) ? gl : 0.0f,
                              rowv ? gm.x : 0.0f,
                              rowv ? gm.y : 0.0f,
                              (rowv && rv) ? gr : 0.0f };

        #pragma unroll
        for (int k = 0; k < 2; ++k) {
            #pragma unroll
            for (int d = 0; d < 3; ++d) {
                const float g     = wg[k + d];
                const float hn    = wh[k + d];
                const bool  ign   = (g != 255.0f);
                const float grv   = (g == 0.0f) ? -1.0f : 1.0f;
                const float delta = hc[k] - hn;
                const bool  keep  = !(grv * delta > 0.0f);
                const float sc    = 4.0f - grv * S[k];
                lacc += (ign && keep) ? sc : 0.0f;
                vcnt += ign ? 1 : 0;
            }
        }
    }

    // ---- block reduce (wave butterfly + LDS across 4 waves) ----
    double l = (double)lacc;
    double v = (double)vcnt;
    for (int off = 32; off > 0; off >>= 1) {
        l += __shfl_down(l, off, 64);
        v += __shfl_down(v, off, 64);
    }
    __shared__ double s_l[NTHR / 64];
    __shared__ double s_v[NTHR / 64];
    const int wave = threadIdx.x >> 6;
    const int lane = threadIdx.x & 63;
    if (lane == 0) { s_l[wave] = l; s_v[wave] = v; }
    __syncthreads();
    if (threadIdx.x == 0) {
        double2 out2;
        out2.x = s_l[0] + s_l[1] + s_l[2] + s_l[3];
        out2.y = s_v[0] + s_v[1] + s_v[2] + s_v[3];
        partial[blockIdx.x] = out2;            // plain store; kernel boundary = visibility
    }
}

// Kernel 2: one block folds NBLK partials in fixed index order (deterministic).
__global__ __launch_bounds__(NTHR) void elev_final3(
    const double2* __restrict__ partial, float* __restrict__ out)
{
    double l = 0.0, v = 0.0;
    for (int idx = threadIdx.x; idx < NBLK; idx += NTHR) {
        const double2 p = partial[idx];
        l += p.x; v += p.y;
    }
    for (int off = 32; off > 0; off >>= 1) {
        l += __shfl_down(l, off, 64);
        v += __shfl_down(v, off, 64);
    }
    __shared__ double s_l[NTHR / 64];
    __shared__ double s_v[NTHR / 64];
    const int wave = threadIdx.x >> 6;
    const int lane = threadIdx.x & 63;
    if (lane == 0) { s_l[wave] = l; s_v[wave] = v; }
    __syncthreads();
    if (threadIdx.x == 0) {
        const double fl = s_l[0] + s_l[1] + s_l[2] + s_l[3];
        const double fv = s_v[0] + s_v[1] + s_v[2] + s_v[3];
        out[0] = (float)(fl / (fv > 1.0 ? fv : 1.0));
    }
}

extern "C" void kernel_launch(void* const* d_in, const int* in_sizes, int n_in,
                              void* d_out, int out_size, void* d_ws, size_t ws_size,
                              hipStream_t stream) {
    const float* pred = (const float*)d_in[0];   // (4,2,512,512) f32
    const float* hts  = (const float*)d_in[1];   // (4,1,512,512) f32
    const float* gt   = (const float*)d_in[2];   // (4,1,512,512) f32
    float* out        = (float*)d_out;
    double2* partial  = (double2*)d_ws;          // 2048 * 16B = 32 KiB

    elev_partial3<<<NBLK, NTHR, 0, stream>>>(pred, hts, gt, partial);
    elev_final3<<<1, NTHR, 0, stream>>>(partial, out);
}

// Round 7
// 13.177 us; speedup vs baseline: 4.4120x; 1.2782x over previous
//
#include <hip/hip_runtime.h>

// B=4, H=512, W=512 (from setup_inputs)
#define B_   4
#define H_   512
#define W_   512
#define HW_  (H_ * W_)

#define NBLK 1024   // 256 spatial blocks x 4 batches; 4 blocks/CU -> 16 waves/CU
#define NTHR 256

// Semantics (verified exact R2-R6, absmax 0.0):
//   c0[p]  = #{b : !(pred[b,1,p] > pred[b,0,p])}                (argmax ties -> 0)
//   S[a,p] = pred[a,0,p]*c0 - pred[a,1,p]*(4-c0)
//   per neighbor (zero-padded gt & heights; pad counts as valid dry):
//     ign = (g != 255); gr = (g==0 ? -1 : 1); delta = hc - hn
//     keep = !(gr*delta > 0)
//     loss += ign && keep ? (4 - gr*S) : 0;  n_valid += ign
//   out = loss / max(n_valid, 1)
__global__ __launch_bounds__(NTHR) void elev_partial4(
    const float* __restrict__ pred,
    const float* __restrict__ hts,
    const float* __restrict__ gt,
    double2* __restrict__ partial)              // NBLK entries, plain stores
{
    const int a     = blockIdx.x >> 8;              // batch 0..3
    const int sb    = blockIdx.x & 255;             // spatial block
    const int chunk = sb * NTHR + threadIdx.x;      // [0, 65536): 4-px chunks
    const int px0   = chunk << 2;
    const int i     = px0 >> 9;
    const int j0    = px0 & (W_ - 1);

    // ---- cross-batch argmax counts for the 4 pixels (keep own batch's values) ----
    int c0k[4] = {0, 0, 0, 0};
    float xs[4] = {0.f, 0.f, 0.f, 0.f};
    float ys[4] = {0.f, 0.f, 0.f, 0.f};
    #pragma unroll
    for (int b = 0; b < B_; ++b) {
        const float* pb = pred + (size_t)(b * 2) * HW_ + px0;
        const float4 x = *(const float4*)(pb);
        const float4 y = *(const float4*)(pb + HW_);
        c0k[0] += (y.x > x.x) ? 0 : 1;
        c0k[1] += (y.y > x.y) ? 0 : 1;
        c0k[2] += (y.z > x.z) ? 0 : 1;
        c0k[3] += (y.w > x.w) ? 0 : 1;
        if (b == a) {
            xs[0] = x.x; xs[1] = x.y; xs[2] = x.z; xs[3] = x.w;
            ys[0] = y.x; ys[1] = y.y; ys[2] = y.z; ys[3] = y.w;
        }
    }
    float S[4];
    #pragma unroll
    for (int k = 0; k < 4; ++k) {
        const float c0f = (float)c0k[k];
        S[k] = xs[k] * c0f - ys[k] * ((float)B_ - c0f);
    }

    const float* hbase = hts + (size_t)a * HW_;
    const float* gbase = gt  + (size_t)a * HW_;

    const float4 hcv = *(const float4*)(hbase + px0);
    const float  hc[4] = { hcv.x, hcv.y, hcv.z, hcv.w };

    const int  jL = (j0 > 0) ? (j0 - 1) : 0;             // clamped, in-bounds
    const int  jR = (j0 < W_ - 4) ? (j0 + 4) : (W_ - 1);
    const bool lv = (j0 > 0);
    const bool rv = (j0 < W_ - 4);

    float lacc = 0.0f;
    int   vcnt = 0;

    #pragma unroll
    for (int dr = 0; dr < 3; ++dr) {
        const int  r    = i + dr - 1;
        const int  rc   = (r < 0) ? 0 : ((r > H_ - 1) ? (H_ - 1) : r);
        const bool rowv = (r == rc);
        const float* hrow = hbase + (size_t)rc * W_;
        const float* grow = gbase + (size_t)rc * W_;

        const float4 hm = *(const float4*)(hrow + j0);
        const float  hl = hrow[jL];
        const float  hr = hrow[jR];
        const float4 gm = *(const float4*)(grow + j0);
        const float  gl = grow[jL];
        const float  gr = grow[jR];

        // 6-wide zero-padded windows (pad entries PARTICIPATE as g=0,h=0)
        const float wh[6] = { (rowv && lv) ? hl : 0.0f,
                              rowv ? hm.x : 0.0f,
                              rowv ? hm.y : 0.0f,
                              rowv ? hm.z : 0.0f,
                              rowv ? hm.w : 0.0f,
                              (rowv && rv) ? hr : 0.0f };
        const float wg[6] = { (rowv && lv) ? gl : 0.0f,
                              rowv ? gm.x : 0.0f,
                              rowv ? gm.y : 0.0f,
                              rowv ? gm.z : 0.0f,
                              rowv ? gm.w : 0.0f,
                              (rowv && rv) ? gr : 0.0f };

        #pragma unroll
        for (int k = 0; k < 4; ++k) {
            #pragma unroll
            for (int d = 0; d < 3; ++d) {
                const float g     = wg[k + d];
                const float hn    = wh[k + d];
                const bool  ign   = (g != 255.0f);
                const float grv   = (g == 0.0f) ? -1.0f : 1.0f;
                const float delta = hc[k] - hn;
                const bool  keep  = !(grv * delta > 0.0f);
                const float sc    = 4.0f - grv * S[k];
                lacc += (ign && keep) ? sc : 0.0f;
                vcnt += ign ? 1 : 0;
            }
        }
    }

    // ---- block reduce (wave butterfly + LDS across 4 waves) ----
    double l = (double)lacc;
    double v = (double)vcnt;
    for (int off = 32; off > 0; off >>= 1) {
        l += __shfl_down(l, off, 64);
        v += __shfl_down(v, off, 64);
    }
    __shared__ double s_l[NTHR / 64];
    __shared__ double s_v[NTHR / 64];
    const int wave = threadIdx.x >> 6;
    const int lane = threadIdx.x & 63;
    if (lane == 0) { s_l[wave] = l; s_v[wave] = v; }
    __syncthreads();
    if (threadIdx.x == 0) {
        double2 out2;
        out2.x = s_l[0] + s_l[1] + s_l[2] + s_l[3];
        out2.y = s_v[0] + s_v[1] + s_v[2] + s_v[3];
        partial[blockIdx.x] = out2;            // plain store; kernel boundary = visibility
    }
}

// Kernel 2: one block folds NBLK partials in fixed index order (deterministic).
__global__ __launch_bounds__(NTHR) void elev_final4(
    const double2* __restrict__ partial, float* __restrict__ out)
{
    double l = 0.0, v = 0.0;
    #pragma unroll
    for (int q = 0; q < NBLK / NTHR; ++q) {
        const double2 p = partial[q * NTHR + threadIdx.x];
        l += p.x; v += p.y;
    }
    for (int off = 32; off > 0; off >>= 1) {
        l += __shfl_down(l, off, 64);
        v += __shfl_down(v, off, 64);
    }
    __shared__ double s_l[NTHR / 64];
    __shared__ double s_v[NTHR / 64];
    const int wave = threadIdx.x >> 6;
    const int lane = threadIdx.x & 63;
    if (lane == 0) { s_l[wave] = l; s_v[wave] = v; }
    __syncthreads();
    if (threadIdx.x == 0) {
        const double fl = s_l[0] + s_l[1] + s_l[2] + s_l[3];
        const double fv = s_v[0] + s_v[1] + s_v[2] + s_v[3];
        out[0] = (float)(fl / (fv > 1.0 ? fv : 1.0));
    }
}

extern "C" void kernel_launch(void* const* d_in, const int* in_sizes, int n_in,
                              void* d_out, int out_size, void* d_ws, size_t ws_size,
                              hipStream_t stream) {
    const float* pred = (const float*)d_in[0];   // (4,2,512,512) f32
    const float* hts  = (const float*)d_in[1];   // (4,1,512,512) f32
    const float* gt   = (const float*)d_in[2];   // (4,1,512,512) f32
    float* out        = (float*)d_out;
    double2* partial  = (double2*)d_ws;          // 1024 * 16B = 16 KiB

    elev_partial4<<<NBLK, NTHR, 0, stream>>>(pred, hts, gt, partial);
    elev_final4<<<1, NTHR, 0, stream>>>(partial, out);
}